// Round 16
// baseline (511.819 us; speedup 1.0000x reference)
//
#include <hip/hip_runtime.h>
#include <hip/hip_bf16.h>
#include <hip/hip_cooperative_groups.h>

namespace cg = cooperative_groups;

// IN_DIM=128, H=8, D=16, H*D=128.

typedef short short8 __attribute__((ext_vector_type(8)));
typedef float f32x4 __attribute__((ext_vector_type(4)));

__device__ __forceinline__ unsigned pack_bf16(float a, float b) {
    unsigned ua = __float_as_uint(a), ub = __float_as_uint(b);
    ua += 0x7fffu + ((ua >> 16) & 1u);          // RNE round to bf16
    ub += 0x7fffu + ((ub >> 16) & 1u);
    return (ua >> 16) | (ub & 0xffff0000u);
}

#define ULO(u) __uint_as_float((u) << 16)
#define UHI(u) __uint_as_float((u) & 0xffff0000u)

// ---------------------------------------------------------------------------
// csr_coop: ONE cooperative kernel replacing prep_all/hist_rank/
// scan_block_sums/scan_final2/fill_kernel (all phases share the same
// 256-thread no-LDS-heavy resource shape; grid.sync() replaces 4 kernel
// boundaries).
//   phase0: blocks [0,24) build swizzled bf16 WT images (32KB per W):
//           uint at [col*256 + ((4kp)^((col&7)<<4))] = pack(W[2kp][col],W[2kp+1][col]);
//           blocks [24,..) zero counts.
//   phase1: hist+rank (rank[i] = atomicAdd(&counts[dst[i]],1))
//   phase2: per-256-chunk sums -> bsums   (blocks < nb)
//   phase3: exclusive scan -> offsets     (blocks < nb; own bsums prefix)
//   phase4: fill srcSorted (no atomics: offsets[dst]+rank)
// Grid: 1024 blocks x 256 (4 blocks/CU guaranteed co-resident).
// ---------------------------------------------------------------------------
__global__ __launch_bounds__(256) void csr_coop(
    const float* __restrict__ W0, const float* __restrict__ W1,
    const float* __restrict__ W2, unsigned char* __restrict__ WTb,
    const int* __restrict__ src, const int* __restrict__ dst,
    int* __restrict__ counts, int* __restrict__ rank,
    int* __restrict__ bsums, int* __restrict__ offsets,
    int* __restrict__ srcSorted, int n, int e, int nb)
{
    cg::grid_group grid = cg::this_grid();
    __shared__ int tmp[256];
    __shared__ int red[4];
    const int b = blockIdx.x, t = threadIdx.x;
    const int gstride = (int)gridDim.x * 256;

    // ---- phase 0 ----
    if (b < 24) {
        const int w   = b >> 3;
        const int idx = (b & 7) * 256 + t;            // [0, 2048)
        const float* W = (w == 0) ? W0 : (w == 1) ? W1 : W2;
        unsigned char* wt = WTb + w * 32768;
        const int kp = idx >> 5;                      // k-pair, [0,64)
        const int c4 = (idx & 31) * 4;                // col group
        const float* Wp = W + (size_t)(2 * kp) * 128 + c4;
        float4 wa = *(const float4*)Wp;
        float4 wb = *(const float4*)(Wp + 128);
        float a0[4] = {wa.x, wa.y, wa.z, wa.w};
        float a1[4] = {wb.x, wb.y, wb.z, wb.w};
#pragma unroll
        for (int i = 0; i < 4; ++i) {
            const int col = c4 + i;
            *(unsigned*)(wt + col * 256 + ((4 * kp) ^ ((col & 7) << 4))) =
                pack_bf16(a0[i], a1[i]);
        }
    } else {
        for (int i = (b - 24) * 256 + t; i < n; i += ((int)gridDim.x - 24) * 256)
            counts[i] = 0;
    }
    grid.sync();

    // ---- phase 1: hist + rank ----
    for (int i = b * 256 + t; i < e; i += gstride)
        rank[i] = atomicAdd(&counts[dst[i]], 1);
    grid.sync();

    // ---- phase 2: per-chunk sums ----
    if (b < nb) {
        const int i = b * 256 + t;
        int v = (i < n) ? counts[i] : 0;
#pragma unroll
        for (int o = 32; o > 0; o >>= 1) v += __shfl_down(v, o, 64);
        if ((t & 63) == 0) red[t >> 6] = v;
        __syncthreads();
        if (t == 0) bsums[b] = red[0] + red[1] + red[2] + red[3];
    }
    grid.sync();

    // ---- phase 3: offsets ----
    if (b < nb) {
        int pre = (t < b) ? bsums[t] : 0;             // nb <= 256
#pragma unroll
        for (int o = 32; o > 0; o >>= 1) pre += __shfl_down(pre, o, 64);
        if ((t & 63) == 0) red[t >> 6] = pre;
        __syncthreads();
        const int base = red[0] + red[1] + red[2] + red[3];

        const int i = b * 256 + t;
        int v = (i < n) ? counts[i] : 0;
        tmp[t] = v;
        __syncthreads();
        for (int o = 1; o < 256; o <<= 1) {
            int u = (t >= o) ? tmp[t - o] : 0;
            __syncthreads();
            tmp[t] += u;
            __syncthreads();
        }
        if (i < n) offsets[i] = base + tmp[t] - v;
        if (i == n) offsets[n] = e;
    }
    grid.sync();

    // ---- phase 4: fill (no atomics) ----
    for (int i = b * 256 + t; i < e; i += gstride)
        srcSorted[offsets[dst[i]] + rank[i]] = src[i];
}

// ---------------------------------------------------------------------------
// MFMA QKV GEMM, register-B variant (r10/r15 structure, best measured).
// BM=64 rows/block, 512 threads = 8 waves (2x4); each wave a 32x32 tile =
// 2x2 frags of mfma_f32_16x16x32_bf16. h staged fp32->bf16 swizzled in LDS;
// A-frags read once; B-frags straight from the swizzled WT image (L2-hot).
// LDS 32KB: [0,16K) h image, [16K,32K) epilogue scratch.
// Planes: Qb/Kb/Vb each [row][64] uints; uint c = cols (2c,2c+1).
// ---------------------------------------------------------------------------
__global__ __launch_bounds__(512) void qkv_gemm(
    const float* __restrict__ h, const unsigned char* __restrict__ WTb,
    const float* __restrict__ b0, const float* __restrict__ b1,
    const float* __restrict__ b2,
    unsigned* __restrict__ qb, unsigned* __restrict__ kb, unsigned* __restrict__ vb,
    int n)
{
    __shared__ __align__(16) unsigned char lds[32768];
    const int tid  = threadIdx.x;
    const int row0 = blockIdx.x * 64;

    for (int idx = tid; idx < 2048; idx += 512) {
        const int row = idx >> 5;
        const int c4  = (idx & 31) * 4;
        float4 v = make_float4(0.f, 0.f, 0.f, 0.f);
        if (row0 + row < n) v = *(const float4*)(h + (size_t)(row0 + row) * 128 + c4);
        *(uint2*)(lds + row * 256 + ((c4 * 2) ^ ((row & 7) << 4))) =
            make_uint2(pack_bf16(v.x, v.y), pack_bf16(v.z, v.w));
    }

    const float* bs[3] = {b0, b1, b2};
    unsigned* planes[3] = {qb, kb, vb};

    const int lane = tid & 63, wave = tid >> 6;
    const int wr = wave >> 2, wc = wave & 3;
    const int lr = lane & 15, lg = lane >> 4;

    __syncthreads();

    short8 af[2][4];
#pragma unroll
    for (int mt = 0; mt < 2; ++mt)
#pragma unroll
        for (int ks = 0; ks < 4; ++ks) {
            const int row = wr * 32 + mt * 16 + lr;
            const int kbyte = ks * 64 + lg * 16;
            af[mt][ks] = *(const short8*)(lds + row * 256 + (kbyte ^ ((row & 7) << 4)));
        }

    for (int w = 0; w < 3; ++w) {
        short8 bf[2][4];
#pragma unroll
        for (int nt = 0; nt < 2; ++nt)
#pragma unroll
            for (int ks = 0; ks < 4; ++ks) {
                const int col = wc * 32 + nt * 16 + lr;
                const int kbyte = ks * 64 + lg * 16;
                bf[nt][ks] = *(const short8*)(
                    WTb + w * 32768 + col * 256 + (kbyte ^ ((col & 7) << 4)));
            }

        f32x4 acc[2][2];
#pragma unroll
        for (int nt = 0; nt < 2; ++nt) {
            const float bv = bs[w][wc * 32 + nt * 16 + lr];
            acc[0][nt] = (f32x4){bv, bv, bv, bv};
            acc[1][nt] = (f32x4){bv, bv, bv, bv};
        }
#pragma unroll
        for (int ks = 0; ks < 4; ++ks)
#pragma unroll
            for (int mt = 0; mt < 2; ++mt)
#pragma unroll
                for (int nt = 0; nt < 2; ++nt)
                    acc[mt][nt] = __builtin_amdgcn_mfma_f32_16x16x32_bf16(
                        af[mt][ks], bf[nt][ks], acc[mt][nt], 0, 0, 0);

        __syncthreads();
        {
            unsigned* epi = (unsigned*)(lds + 16384);
#pragma unroll
            for (int mt = 0; mt < 2; ++mt)
#pragma unroll
                for (int nt = 0; nt < 2; ++nt) {
                    const int col = wc * 32 + nt * 16 + lr;
#pragma unroll
                    for (int r = 0; r < 4; ++r) {
                        const int row = wr * 32 + mt * 16 + lg * 4 + r;
                        const float v  = acc[mt][nt][r];
                        const float vn = __shfl_xor(v, 1);
                        if (!(lane & 1)) epi[row * 64 + (col >> 1)] = pack_bf16(v, vn);
                    }
                }
        }
        __syncthreads();
        {
            const uint4* s = (const uint4*)(lds + 16384);
            uint4* d = (uint4*)(planes[w] + (size_t)row0 * 64);
            d[tid]       = s[tid];
            d[tid + 512] = s[tid + 512];
        }
    }
}

// ---------------------------------------------------------------------------
// Gather (r15 structure, byte-identical): one wave per node, TWO edges per
// iteration (half-wave each). half = lane>>5, l5 = lane&31 owns dims
// 4*l5..4*l5+3; head = l5>>2 -> 4-lane reduce (xor 1,2). Per pair: uint2
// from Kb + uint2 from Vb. exp2-form softmax; scores clamped before softmax
// -> no segment-max needed (shift invariance).
// ---------------------------------------------------------------------------
__global__ __launch_bounds__(256) void mha_node(
    const unsigned* __restrict__ Qb, const uint2* __restrict__ Kb2,
    const uint2* __restrict__ Vb2,
    const int* __restrict__ offsets, const int* __restrict__ srcSorted,
    float* __restrict__ out, int n)
{
    const int lane = threadIdx.x & 63;
    const int node = (blockIdx.x * blockDim.x + threadIdx.x) >> 6;
    if (node >= n) return;
    const int half = lane >> 5;
    const int l5   = lane & 31;

    const float QS = 0.25f * 1.44269504089f;       // (1/sqrt(16)) * log2(e)
    const float CL = 5.f * 1.44269504089f;

    const uint2 qu = *(const uint2*)(Qb + (size_t)node * 64 + 2 * l5);
    const float q0 = ULO(qu.x) * QS, q1 = UHI(qu.x) * QS;
    const float q2 = ULO(qu.y) * QS, q3 = UHI(qu.y) * QS;

    const int beg = offsets[node], end = offsets[node + 1];
    float a0 = 0.f, a1 = 0.f, a2 = 0.f, a3 = 0.f, lsum = 0.f;

#define PAIR_COMPUTE(ku, vu, val)                                       \
    {                                                                   \
        float prod = ULO((ku).x) * q0;                                  \
        prod = fmaf(UHI((ku).x), q1, prod);                             \
        prod = fmaf(ULO((ku).y), q2, prod);                             \
        prod = fmaf(UHI((ku).y), q3, prod);                             \
        prod += __shfl_xor(prod, 1);                                    \
        prod += __shfl_xor(prod, 2);                                    \
        float sc = fminf(CL, fmaxf(-CL, prod));                         \
        float p = (val) ? exp2f(sc) : 0.f;                              \
        lsum += p;                                                      \
        a0 = fmaf(p, ULO((vu).x), a0);                                  \
        a1 = fmaf(p, UHI((vu).x), a1);                                  \
        a2 = fmaf(p, ULO((vu).y), a2);                                  \
        a3 = fmaf(p, UHI((vu).y), a3);                                  \
    }

    for (int j0 = beg; j0 < end; j0 += 64) {
        const int rem = end - j0;
        const int cnt = rem < 64 ? rem : 64;
        int myS = (lane < cnt) ? srcSorted[j0 + lane] : 0;

        int t = 0;
        for (; t + 8 <= cnt; t += 8) {
            uint2 ku[4], vu[4];
#pragma unroll
            for (int u = 0; u < 4; ++u) {
                int s = __shfl(myS, t + 2 * u + half);
                ku[u] = Kb2[(size_t)s * 32 + l5];
                vu[u] = Vb2[(size_t)s * 32 + l5];
            }
#pragma unroll
            for (int u = 0; u < 4; ++u) PAIR_COMPUTE(ku[u], vu[u], true);
        }
        for (; t < cnt; t += 2) {
            const int ei = t + half;
            const bool val = ei < cnt;
            int s = __shfl(myS, val ? ei : cnt - 1);
            uint2 ku0 = Kb2[(size_t)s * 32 + l5];
            uint2 vu0 = Vb2[(size_t)s * 32 + l5];
            PAIR_COMPUTE(ku0, vu0, val);
        }
    }

    lsum += __shfl_xor(lsum, 32);
    a0 += __shfl_xor(a0, 32);
    a1 += __shfl_xor(a1, 32);
    a2 += __shfl_xor(a2, 32);
    a3 += __shfl_xor(a3, 32);

    if (half == 0) {
        const float inv = (lsum > 0.f) ? 1.f / lsum : 0.f;
        *(float4*)(out + (size_t)node * 128 + 4 * l5) =
            make_float4(a0 * inv, a1 * inv, a2 * inv, a3 * inv);
    }
}

// ---------------------------------------------------------------------------
extern "C" void kernel_launch(void* const* d_in, const int* in_sizes, int n_in,
                              void* d_out, int out_size, void* d_ws, size_t ws_size,
                              hipStream_t stream) {
    const float* h  = (const float*)d_in[0];
    const float* Wq = (const float*)d_in[1];
    const float* bq = (const float*)d_in[2];
    const float* Wk = (const float*)d_in[3];
    const float* bk = (const float*)d_in[4];
    const float* Wv = (const float*)d_in[5];
    const float* bv = (const float*)d_in[6];
    const int*   src = (const int*)d_in[7];
    const int*   dst = (const int*)d_in[8];
    float* out = (float*)d_out;

    int n = in_sizes[0] / 128;
    int e = in_sizes[7];
    const int nblk = (n + 63) / 64;        // GEMM blocks
    const int npad = nblk * 64;            // padded rows
    int nb = (n + 255) / 256;              // scan chunks (<=256; n=50000 -> 196)

    char* ws = (char*)d_ws;
    size_t off = 0;
    auto alloc = [&](size_t bytes) {
        char* p = ws + off;
        off = (off + bytes + 255) & ~(size_t)255;
        return p;
    };
    unsigned char* WTb = (unsigned char*)alloc(3 * 32768);
    unsigned* Qb       = (unsigned*)alloc((size_t)npad * 64 * 4);
    unsigned* Kb       = (unsigned*)alloc((size_t)npad * 64 * 4);
    unsigned* Vb       = (unsigned*)alloc((size_t)npad * 64 * 4);
    int* counts        = (int*)alloc((size_t)n * sizeof(int));
    int* offsets       = (int*)alloc((size_t)(n + 1) * sizeof(int));
    int* rank          = (int*)alloc((size_t)e * sizeof(int));
    int* bsums         = (int*)alloc((size_t)nb * sizeof(int));
    int* srcSorted     = (int*)alloc((size_t)e * sizeof(int));
    (void)ws_size; (void)n_in; (void)out_size;

    void* args[] = {
        (void*)&Wq, (void*)&Wk, (void*)&Wv, (void*)&WTb,
        (void*)&src, (void*)&dst,
        (void*)&counts, (void*)&rank, (void*)&bsums, (void*)&offsets,
        (void*)&srcSorted, (void*)&n, (void*)&e, (void*)&nb
    };
    hipLaunchCooperativeKernel((const void*)csr_coop, dim3(1024), dim3(256),
                               args, 0, stream);

    qkv_gemm<<<nblk, 512, 0, stream>>>(h, WTb, bq, bk, bv, Qb, Kb, Vb, n);
    mha_node<<<((size_t)n * 64 + 255) / 256, 256, 0, stream>>>(
        Qb, (const uint2*)Kb, (const uint2*)Vb, offsets, srcSorted, out, n);
}

// Round 17
// 142.129 us; speedup vs baseline: 3.6011x; 3.6011x over previous
//
#include <hip/hip_runtime.h>
#include <hip/hip_bf16.h>

// IN_DIM=128, H=8, D=16, H*D=128.

typedef short short8 __attribute__((ext_vector_type(8)));
typedef float f32x4 __attribute__((ext_vector_type(4)));

__device__ __forceinline__ unsigned pack_bf16(float a, float b) {
    unsigned ua = __float_as_uint(a), ub = __float_as_uint(b);
    ua += 0x7fffu + ((ua >> 16) & 1u);          // RNE round to bf16
    ub += 0x7fffu + ((ub >> 16) & 1u);
    return (ua >> 16) | (ub & 0xffff0000u);
}

#define ULO(u) __uint_as_float((u) << 16)
#define UHI(u) __uint_as_float((u) & 0xffff0000u)

// ---------------------------------------------------------------------------
// prep_all: [0,24): build swizzled bf16 WT images (32KB per W);
//           [24,...): zero counts.
// WT image: uint at [col*256 + ((4kp) ^ ((col&7)<<4))] = pack(W[2kp][col], W[2kp+1][col]).
// ---------------------------------------------------------------------------
__global__ __launch_bounds__(256) void prep_all(
    const float* __restrict__ W0, const float* __restrict__ W1,
    const float* __restrict__ W2, unsigned char* __restrict__ WTb,
    int* __restrict__ counts, int n)
{
    const int b = blockIdx.x;
    if (b < 24) {
        const int w   = b >> 3;
        const int idx = (b & 7) * 256 + threadIdx.x;          // [0, 2048)
        const float* W = (w == 0) ? W0 : (w == 1) ? W1 : W2;
        unsigned char* wt = WTb + w * 32768;
        const int kp = idx >> 5;           // k-pair (2kp,2kp+1), [0,64)
        const int c4 = (idx & 31) * 4;     // col group
        const float* Wp = W + (size_t)(2 * kp) * 128 + c4;
        float4 wa = *(const float4*)Wp;
        float4 wb = *(const float4*)(Wp + 128);
        float a0[4] = {wa.x, wa.y, wa.z, wa.w};
        float a1[4] = {wb.x, wb.y, wb.z, wb.w};
#pragma unroll
        for (int i = 0; i < 4; ++i) {
            const int col = c4 + i;
            *(unsigned*)(wt + col * 256 + ((4 * kp) ^ ((col & 7) << 4))) =
                pack_bf16(a0[i], a1[i]);
        }
    } else {
        const int i = (b - 24) * 256 + threadIdx.x;
        if (i < n) counts[i] = 0;
    }
}

// ---------------------------------------------------------------------------
// hist_rank: histogram AND per-edge rank (the atomicAdd return) so the later
// fill needs no atomics.
// ---------------------------------------------------------------------------
__global__ void hist_rank(const int* __restrict__ dst, int* __restrict__ counts,
                          int* __restrict__ rank, int e) {
    int i = blockIdx.x * blockDim.x + threadIdx.x;
    if (i < e) rank[i] = atomicAdd(&counts[dst[i]], 1);
}

__global__ void scan_block_sums(const int* __restrict__ counts, int* __restrict__ bsums, int nelem) {
    __shared__ int red[4];
    int i = blockIdx.x * 256 + threadIdx.x;
    int v = (i < nelem) ? counts[i] : 0;
#pragma unroll
    for (int o = 32; o > 0; o >>= 1) v += __shfl_down(v, o, 64);
    if ((threadIdx.x & 63) == 0) red[threadIdx.x >> 6] = v;
    __syncthreads();
    if (threadIdx.x == 0) bsums[blockIdx.x] = red[0] + red[1] + red[2] + red[3];
}

// scan_final2: computes its own exclusive prefix of bsums (nb<=256), then
// block-scans counts and writes offsets. offsets[nelem]=e by thread i==nelem.
__global__ void scan_final2(const int* __restrict__ counts, const int* __restrict__ bsums,
                            int* __restrict__ offsets, int nelem, int e) {
    __shared__ int tmp[256];
    __shared__ int red[4];
    const int t = threadIdx.x;

    int pre = (t < blockIdx.x) ? bsums[t] : 0;
#pragma unroll
    for (int o = 32; o > 0; o >>= 1) pre += __shfl_down(pre, o, 64);
    if ((t & 63) == 0) red[t >> 6] = pre;
    __syncthreads();
    const int base = red[0] + red[1] + red[2] + red[3];

    const int i = blockIdx.x * 256 + t;
    int v = (i < nelem) ? counts[i] : 0;
    tmp[t] = v;
    __syncthreads();
    for (int o = 1; o < 256; o <<= 1) {
        int u = (t >= o) ? tmp[t - o] : 0;
        __syncthreads();
        tmp[t] += u;
        __syncthreads();
    }
    if (i < nelem) offsets[i] = base + tmp[t] - v;
    if (i == nelem) offsets[nelem] = e;
}

// fill: no atomics — position comes from offsets[dst] + rank.
__global__ void fill_kernel(const int* __restrict__ src, const int* __restrict__ dst,
                            const int* __restrict__ rank, const int* __restrict__ offsets,
                            int* __restrict__ srcSorted, int e) {
    int i = blockIdx.x * blockDim.x + threadIdx.x;
    if (i < e) srcSorted[offsets[dst[i]] + rank[i]] = src[i];
}

// ---------------------------------------------------------------------------
// MFMA QKV GEMM, register-B variant (r10 structure, best measured).
// BM=64 rows/block, 512 threads = 8 waves (2x4); each wave a 32x32 tile =
// 2x2 frags of mfma_f32_16x16x32_bf16.
// - h staged fp32->bf16 swizzled directly into LDS.
// - A-frags loaded from LDS ONCE (shared across all 3 Ws).
// - B-frags loaded per-W straight from the prebuilt swizzled WT image in
//   global memory (L2-resident broadcast) -> no WT LDS staging.
// LDS 32KB: [0,16K) h image, [16K,32K) epilogue scratch.
// Planes: Qb/Kb/Vb each [row][64] uints; uint c = cols (2c,2c+1).
// ---------------------------------------------------------------------------
__global__ __launch_bounds__(512) void qkv_gemm(
    const float* __restrict__ h, const unsigned char* __restrict__ WTb,
    const float* __restrict__ b0, const float* __restrict__ b1,
    const float* __restrict__ b2,
    unsigned* __restrict__ qb, unsigned* __restrict__ kb, unsigned* __restrict__ vb,
    int n)
{
    __shared__ __align__(16) unsigned char lds[32768];
    const int tid  = threadIdx.x;
    const int row0 = blockIdx.x * 64;

    // ---- stage h tile directly: fp32 -> bf16, swizzled 256B rows ----
    for (int idx = tid; idx < 2048; idx += 512) {
        const int row = idx >> 5;
        const int c4  = (idx & 31) * 4;
        float4 v = make_float4(0.f, 0.f, 0.f, 0.f);
        if (row0 + row < n) v = *(const float4*)(h + (size_t)(row0 + row) * 128 + c4);
        *(uint2*)(lds + row * 256 + ((c4 * 2) ^ ((row & 7) << 4))) =
            make_uint2(pack_bf16(v.x, v.y), pack_bf16(v.z, v.w));
    }

    const float* bs[3] = {b0, b1, b2};
    unsigned* planes[3] = {qb, kb, vb};

    const int lane = tid & 63, wave = tid >> 6;
    const int wr = wave >> 2, wc = wave & 3;       // 2x4 wave grid
    const int lr = lane & 15, lg = lane >> 4;

    __syncthreads();

    // ---- A-frags once (depend only on h) ----
    short8 af[2][4];
#pragma unroll
    for (int mt = 0; mt < 2; ++mt)
#pragma unroll
        for (int ks = 0; ks < 4; ++ks) {
            const int row = wr * 32 + mt * 16 + lr;
            const int kbyte = ks * 64 + lg * 16;
            af[mt][ks] = *(const short8*)(lds + row * 256 + (kbyte ^ ((row & 7) << 4)));
        }

    for (int w = 0; w < 3; ++w) {
        // ---- B-frags straight from global WT image (L2 broadcast) ----
        short8 bf[2][4];
#pragma unroll
        for (int nt = 0; nt < 2; ++nt)
#pragma unroll
            for (int ks = 0; ks < 4; ++ks) {
                const int col = wc * 32 + nt * 16 + lr;
                const int kbyte = ks * 64 + lg * 16;
                bf[nt][ks] = *(const short8*)(
                    WTb + w * 32768 + col * 256 + (kbyte ^ ((col & 7) << 4)));
            }

        f32x4 acc[2][2];
#pragma unroll
        for (int nt = 0; nt < 2; ++nt) {
            const float bv = bs[w][wc * 32 + nt * 16 + lr];
            acc[0][nt] = (f32x4){bv, bv, bv, bv};
            acc[1][nt] = (f32x4){bv, bv, bv, bv};
        }
#pragma unroll
        for (int ks = 0; ks < 4; ++ks)
#pragma unroll
            for (int mt = 0; mt < 2; ++mt)
#pragma unroll
                for (int nt = 0; nt < 2; ++nt)
                    acc[mt][nt] = __builtin_amdgcn_mfma_f32_16x16x32_bf16(
                        af[mt][ks], bf[nt][ks], acc[mt][nt], 0, 0, 0);

        __syncthreads();   // epi region free (prev copy-out finished)
        {   // epi: even lanes write packed pair -> [row][colpair] (64x64 uints)
            unsigned* epi = (unsigned*)(lds + 16384);
#pragma unroll
            for (int mt = 0; mt < 2; ++mt)
#pragma unroll
                for (int nt = 0; nt < 2; ++nt) {
                    const int col = wc * 32 + nt * 16 + lr;
#pragma unroll
                    for (int r = 0; r < 4; ++r) {
                        const int row = wr * 32 + mt * 16 + lg * 4 + r;
                        const float v  = acc[mt][nt][r];
                        const float vn = __shfl_xor(v, 1);
                        if (!(lane & 1)) epi[row * 64 + (col >> 1)] = pack_bf16(v, vn);
                    }
                }
        }
        __syncthreads();
        {   // coalesced copy-out: 1024 uint4 = 64 rows x 256B
            const uint4* s = (const uint4*)(lds + 16384);
            uint4* d = (uint4*)(planes[w] + (size_t)row0 * 64);
            d[tid]       = s[tid];
            d[tid + 512] = s[tid + 512];
        }
    }
}

// ---------------------------------------------------------------------------
// Gather: one wave per node, TWO edges per iteration (half-wave each).
// half = lane>>5 (edge select), l5 = lane&31 owns dims 4*l5..4*l5+3;
// head = l5>>2 -> 4-lane reduce (xor 1,2). Per pair: uint2 from Kb + uint2
// from Vb (each half-wave reads a full 256B row, coalesced). exp2-form
// softmax: log2(e) folded into q scale, clamp at +-5*log2(e). Scores clamped
// before softmax -> no segment-max needed (shift invariance).
// ---------------------------------------------------------------------------
__global__ __launch_bounds__(256) void mha_node(
    const unsigned* __restrict__ Qb, const uint2* __restrict__ Kb2,
    const uint2* __restrict__ Vb2,
    const int* __restrict__ offsets, const int* __restrict__ srcSorted,
    float* __restrict__ out, int n)
{
    const int lane = threadIdx.x & 63;
    const int node = (blockIdx.x * blockDim.x + threadIdx.x) >> 6;
    if (node >= n) return;
    const int half = lane >> 5;
    const int l5   = lane & 31;

    const float QS = 0.25f * 1.44269504089f;       // (1/sqrt(16)) * log2(e)
    const float CL = 5.f * 1.44269504089f;

    const uint2 qu = *(const uint2*)(Qb + (size_t)node * 64 + 2 * l5);
    const float q0 = ULO(qu.x) * QS, q1 = UHI(qu.x) * QS;
    const float q2 = ULO(qu.y) * QS, q3 = UHI(qu.y) * QS;

    const int beg = offsets[node], end = offsets[node + 1];
    float a0 = 0.f, a1 = 0.f, a2 = 0.f, a3 = 0.f, lsum = 0.f;

#define PAIR_COMPUTE(ku, vu, val)                                       \
    {                                                                   \
        float prod = ULO((ku).x) * q0;                                  \
        prod = fmaf(UHI((ku).x), q1, prod);                             \
        prod = fmaf(ULO((ku).y), q2, prod);                             \
        prod = fmaf(UHI((ku).y), q3, prod);                             \
        prod += __shfl_xor(prod, 1);                                    \
        prod += __shfl_xor(prod, 2);                                    \
        float sc = fminf(CL, fmaxf(-CL, prod));                         \
        float p = (val) ? exp2f(sc) : 0.f;                              \
        lsum += p;                                                      \
        a0 = fmaf(p, ULO((vu).x), a0);                                  \
        a1 = fmaf(p, UHI((vu).x), a1);                                  \
        a2 = fmaf(p, ULO((vu).y), a2);                                  \
        a3 = fmaf(p, UHI((vu).y), a3);                                  \
    }

    for (int j0 = beg; j0 < end; j0 += 64) {
        const int rem = end - j0;
        const int cnt = rem < 64 ? rem : 64;
        int myS = (lane < cnt) ? srcSorted[j0 + lane] : 0;

        int t = 0;
        for (; t + 8 <= cnt; t += 8) {        // 4 pairs = 8 edges per batch
            uint2 ku[4], vu[4];
#pragma unroll
            for (int u = 0; u < 4; ++u) {
                int s = __shfl(myS, t + 2 * u + half);
                ku[u] = Kb2[(size_t)s * 32 + l5];
                vu[u] = Vb2[(size_t)s * 32 + l5];
            }
#pragma unroll
            for (int u = 0; u < 4; ++u) PAIR_COMPUTE(ku[u], vu[u], true);
        }
        for (; t < cnt; t += 2) {             // tail: one pair at a time
            const int ei = t + half;
            const bool val = ei < cnt;
            int s = __shfl(myS, val ? ei : cnt - 1);
            uint2 ku0 = Kb2[(size_t)s * 32 + l5];
            uint2 vu0 = Vb2[(size_t)s * 32 + l5];
            PAIR_COMPUTE(ku0, vu0, val);
        }
    }

    // combine the two halves (same dims, alternating edges)
    lsum += __shfl_xor(lsum, 32);
    a0 += __shfl_xor(a0, 32);
    a1 += __shfl_xor(a1, 32);
    a2 += __shfl_xor(a2, 32);
    a3 += __shfl_xor(a3, 32);

    if (half == 0) {
        const float inv = (lsum > 0.f) ? 1.f / lsum : 0.f;
        *(float4*)(out + (size_t)node * 128 + 4 * l5) =
            make_float4(a0 * inv, a1 * inv, a2 * inv, a3 * inv);
    }
}

// ---------------------------------------------------------------------------
extern "C" void kernel_launch(void* const* d_in, const int* in_sizes, int n_in,
                              void* d_out, int out_size, void* d_ws, size_t ws_size,
                              hipStream_t stream) {
    const float* h  = (const float*)d_in[0];
    const float* Wq = (const float*)d_in[1];
    const float* bq = (const float*)d_in[2];
    const float* Wk = (const float*)d_in[3];
    const float* bk = (const float*)d_in[4];
    const float* Wv = (const float*)d_in[5];
    const float* bv = (const float*)d_in[6];
    const int*   src = (const int*)d_in[7];
    const int*   dst = (const int*)d_in[8];
    float* out = (float*)d_out;

    const int n = in_sizes[0] / 128;
    const int e = in_sizes[7];
    const int nblk = (n + 63) / 64;        // GEMM blocks
    const int npad = nblk * 64;            // padded rows
    const int nb = (n + 255) / 256;        // scan blocks (<=256; n=50000 -> 196)

    char* ws = (char*)d_ws;
    size_t off = 0;
    auto alloc = [&](size_t bytes) {
        char* p = ws + off;
        off = (off + bytes + 255) & ~(size_t)255;
        return p;
    };
    unsigned char* WTb = (unsigned char*)alloc(3 * 32768);
    unsigned* Qb       = (unsigned*)alloc((size_t)npad * 64 * 4);
    unsigned* Kb       = (unsigned*)alloc((size_t)npad * 64 * 4);
    unsigned* Vb       = (unsigned*)alloc((size_t)npad * 64 * 4);
    int* counts        = (int*)alloc((size_t)n * sizeof(int));
    int* offsets       = (int*)alloc((size_t)(n + 1) * sizeof(int));
    int* rank          = (int*)alloc((size_t)e * sizeof(int));
    int* bsums         = (int*)alloc((size_t)nb * sizeof(int));
    int* srcSorted     = (int*)alloc((size_t)e * sizeof(int));
    (void)ws_size; (void)n_in; (void)out_size;

    prep_all<<<24 + nb, 256, 0, stream>>>(Wq, Wk, Wv, WTb, counts, n);
    hist_rank<<<(e + 255) / 256, 256, 0, stream>>>(dst, counts, rank, e);
    scan_block_sums<<<nb, 256, 0, stream>>>(counts, bsums, n);
    scan_final2<<<nb, 256, 0, stream>>>(counts, bsums, offsets, n, e);
    fill_kernel<<<(e + 255) / 256, 256, 0, stream>>>(src, dst, rank, offsets, srcSorted, e);
    qkv_gemm<<<nblk, 512, 0, stream>>>(h, WTb, bq, bk, bv, Qb, Kb, Vb, n);
    mha_node<<<((size_t)n * 64 + 255) / 256, 256, 0, stream>>>(
        Qb, (const uint2*)Kb, (const uint2*)Vb, offsets, srcSorted, out, n);
}